// Round 1
// 248.201 us; speedup vs baseline: 1.1138x; 1.1138x over previous
//
#include <hip/hip_runtime.h>
#include <cstdint>
#include <cstddef>

#define N_ 32
#define C_ 256
#define H_ 56
#define W_ 56

typedef int v4i __attribute__((ext_vector_type(4)));

// ---- workspace layout ----
// sx: padded sign-activations, i8, [n][58 rows][68 w][256 c], chunk-swizzled:
//     16B-chunk ch of position (row,w) lives at slot (ch + w) & 15.
static constexpr size_t SX_BYTES = (size_t)N_ * 58 * 68 * 256;   // 32,309,248
static constexpr size_t WB_OFF   = SX_BYTES;
static constexpr size_t WB_BYTES = 36ull * 16 * 64 * 16;         // 589,824
static constexpr size_t SC_OFF   = WB_OFF + WB_BYTES;            // 256 floats

// ---------------- kernel 0: zero only the halo cells conv reads ----------------
// conv reads positions w = 0..57 of rows 0..57. pack_x writes rows 1..56, w 1..56.
__global__ __launch_bounds__(256) void zero_halo(char* __restrict__ sx) {
    int row = blockIdx.x;      // 0..57
    int n   = blockIdx.y;
    v4i z = {0, 0, 0, 0};
    char* base = sx + ((size_t)n * 58 + row) * (68 * 256);
    if (row == 0 || row == 57) {
        for (int i = threadIdx.x; i < 58 * 16; i += 256)
            *(v4i*)(base + (size_t)i * 16) = z;
    } else {
        int tid = threadIdx.x;
        if (tid < 32) {
            int wpos = (tid >> 4) * 57;       // w = 0 or 57
            int ch   = tid & 15;              // zeros are swizzle-invariant
            *(v4i*)(base + ((size_t)wpos * 16 + ch) * 16) = z;
        }
    }
}

// ---------------- kernel 1: pack x signs -> NHWC i8 (padded, pre-swizzled) ----
// One block owns a 64-hw tile x ALL 256 channels -> full-line coalesced stores.
__global__ __launch_bounds__(256) void pack_x(const float* __restrict__ x,
                                              char* __restrict__ sx) {
    __shared__ float tile[64 * 65];     // 16.6 KB
    __shared__ char  ob[64 * 256];      // 16 KB packed output tile
    int tid = threadIdx.x;
    int hw0 = blockIdx.x * 64;          // 49 tiles cover 3136 exactly
    int n   = blockIdx.y;

    int cl   = tid >> 6, hwl = tid & 63;
    int hwl2 = tid >> 2, cq  = tid & 3;

    for (int cb = 0; cb < 4; ++cb) {
        const float* xb = x + ((size_t)n * C_ + cb * 64) * 3136 + hw0;
#pragma unroll
        for (int i = 0; i < 16; ++i) {
            int cloc = i * 4 + cl;
            tile[cloc * 65 + hwl] = xb[(size_t)cloc * 3136 + hwl];   // coalesced
        }
        __syncthreads();
        int words[4];
#pragma unroll
        for (int g = 0; g < 4; ++g) {
            int word = 0;
#pragma unroll
            for (int b = 0; b < 4; ++b) {
                float v = tile[(cq * 16 + g * 4 + b) * 65 + hwl2];
                int s = (v > 0.0f) - (v < 0.0f);    // exact sign, 0 at 0
                word |= (s & 0xff) << (8 * b);
            }
            words[g] = word;
        }
        v4i o4 = {words[0], words[1], words[2], words[3]};
        int ch   = cb * 4 + cq;                 // output 16B-chunk index 0..15
        int slot = (ch + hwl2) & 15;            // LDS-side rotation (bank spread)
        *(v4i*)(ob + hwl2 * 256 + slot * 16) = o4;
        __syncthreads();
    }

    // copy-out: contiguous full 256B lines; apply GLOBAL swizzle slot=(ch+wpad)&15
#pragma unroll
    for (int j = 0; j < 4; ++j) {
        int i = tid + j * 256;                  // 0..1023 chunk index in tile
        int hwl3 = i >> 4, ch = i & 15;
        v4i v = *(const v4i*)(ob + hwl3 * 256 + ((ch + hwl3) & 15) * 16);
        int hw = hw0 + hwl3;
        int h = hw / 56, w = hw - h * 56;
        int slot = (ch + (w + 1)) & 15;         // pre-swizzle on padded w index
        *(v4i*)(sx + (((size_t)n * 58 + h + 1) * 68 + (w + 1)) * 256 + slot * 16) = v;
    }
}

// ---------------- kernel 2: binarize weights into MFMA B-fragment layout ----
__global__ __launch_bounds__(256) void pack_w(const float* __restrict__ wt,
                                              char* __restrict__ wB,
                                              float* __restrict__ scaleg) {
    __shared__ double red[256];
    int o = blockIdx.x, tid = threadIdx.x;
    const float* wo = wt + (size_t)o * 2304;

    double s = 0;
    for (int j = tid; j < 2304; j += 256) s += (double)wo[j];
    red[tid] = s;
    __syncthreads();
    for (int k = 128; k > 0; k >>= 1) {
        if (tid < k) red[tid] += red[tid + k];
        __syncthreads();
    }
    double mean = red[0] / 2304.0;
    __syncthreads();

    double s2 = 0;
    for (int j = tid; j < 2304; j += 256) s2 += fabs((double)wo[j] - mean);
    red[tid] = s2;
    __syncthreads();
    for (int k = 128; k > 0; k >>= 1) {
        if (tid < k) red[tid] += red[tid + k];
        __syncthreads();
    }
    if (tid == 0) scaleg[o] = (float)(red[0] / 2304.0);

    if (tid < 144) {
        int kiter = tid >> 2, q = tid & 3;     // kiter 0..35, q = k-quad
        int tap = kiter >> 2, cb = kiter & 3;
        int kh = tap / 3, kw = tap - kh * 3;
        int words[4];
        for (int g = 0; g < 4; ++g) {
            int word = 0;
            for (int b = 0; b < 4; ++b) {
                int c = cb * 64 + q * 16 + g * 4 + b;
                double v = (double)wo[c * 9 + kh * 3 + kw];
                int sg = (v > mean) - (v < mean);
                word |= (sg & 0xff) << (8 * b);
            }
            words[g] = word;
        }
        v4i pk = {words[0], words[1], words[2], words[3]};
        *(v4i*)(wB + (((size_t)kiter * 16 + (o >> 4)) * 64 + q * 16 + (o & 15)) * 16) = pk;
    }
}

// ---------------- kernel 3: i8 MFMA implicit-GEMM conv, 2 rows/block ----------
// block = (row-pair hp, n), 256 threads = 4 waves. Fused m = row*56 + w = 112
// = 7 m-frags of 16 (zero padding waste). Each wave: 7 mf x 4 of, K = 36 iters.
// LDS: 4 input rows, 58 positions wide, content pre-swizzled by pack_x.
__global__ __launch_bounds__(256, 2) void conv_mfma(const char* __restrict__ sx,
                                                    const v4i* __restrict__ wB,
                                                    const float* __restrict__ scaleg,
                                                    float* __restrict__ out) {
    __shared__ char xs[4 * 58 * 256];   // 59,392 B -> 2 blocks/CU
    int tid = threadIdx.x;
    int wave = tid >> 6, lane = tid & 63;
    int hp = blockIdx.x, n = blockIdx.y;
    int h0 = hp * 2;

    // stage 4 padded rows (sx rows h0..h0+3), linear copy (swizzle pre-baked)
    const char* src = sx + ((size_t)n * 58 + h0) * (68 * 256);
    for (int i = tid; i < 4 * 58 * 16; i += 256) {
        int pos = i >> 4;                    // row*58 + w
        int row = pos / 58;
        int w   = pos - row * 58;
        v4i v = *(const v4i*)(src + ((size_t)(row * 68 + w) << 8) + ((size_t)(i & 15) << 4));
        *(v4i*)(xs + (size_t)i * 16) = v;
    }

    int lm = lane & 15, q = lane >> 4;

    // per-m-frag geometry: m = mf*16 + lm -> (row offset, w offset)
    int wof[7], ro[7];
#pragma unroll
    for (int mf = 0; mf < 7; ++mf) {
        int m = mf * 16 + lm;
        int r = (m >= 56) ? 1 : 0;
        ro[mf]  = r;
        wof[mf] = m - 56 * r;
    }

    v4i acc[7][4];
#pragma unroll
    for (int mf = 0; mf < 7; ++mf)
#pragma unroll
        for (int of = 0; of < 4; ++of) { v4i z = {0, 0, 0, 0}; acc[mf][of] = z; }

    const v4i* wBw = wB + (size_t)(wave * 4) * 64 + lane;   // + k*1024 + of*64

    __syncthreads();

    v4i bA[4], bB[4], aA[7], aB[7];

    // prologue: b and a for kiter 0 (dh=0, dw=0, cb=0)
#pragma unroll
    for (int of = 0; of < 4; ++of) bA[of] = wBw[of * 64];
    {
        int cbq = q;
#pragma unroll
        for (int mf = 0; mf < 7; ++mf) {
            int win  = wof[mf];
            int pos  = ro[mf] * 58 + win;
            int phys = (pos << 4) | ((cbq + win) & 15);
            aA[mf] = *(const v4i*)(xs + ((size_t)phys << 4));
        }
    }

    for (int k2 = 0; k2 < 18; ++k2) {
        int k0 = 2 * k2, k1 = k0 + 1;
        // prefetch b,a for k1
#pragma unroll
        for (int of = 0; of < 4; ++of) bB[of] = wBw[(size_t)k1 * 1024 + of * 64];
        {
            int tap = k1 >> 2, cb = k1 & 3;
            int dh = tap / 3, dw = tap - dh * 3;
            int cbq = cb * 4 + q;
#pragma unroll
            for (int mf = 0; mf < 7; ++mf) {
                int win  = wof[mf] + dw;
                int pos  = (dh + ro[mf]) * 58 + win;
                int phys = (pos << 4) | ((cbq + win) & 15);
                aB[mf] = *(const v4i*)(xs + ((size_t)phys << 4));
            }
        }
        // MFMAs for k0
#pragma unroll
        for (int mf = 0; mf < 7; ++mf)
#pragma unroll
            for (int of = 0; of < 4; ++of)
                acc[mf][of] = __builtin_amdgcn_mfma_i32_16x16x64_i8(
                    aA[mf], bA[of], acc[mf][of], 0, 0, 0);
        // prefetch b,a for k0+2
        if (k2 < 17) {
            int kn = k0 + 2;
#pragma unroll
            for (int of = 0; of < 4; ++of) bA[of] = wBw[(size_t)kn * 1024 + of * 64];
            int tap = kn >> 2, cb = kn & 3;
            int dh = tap / 3, dw = tap - dh * 3;
            int cbq = cb * 4 + q;
#pragma unroll
            for (int mf = 0; mf < 7; ++mf) {
                int win  = wof[mf] + dw;
                int pos  = (dh + ro[mf]) * 58 + win;
                int phys = (pos << 4) | ((cbq + win) & 15);
                aA[mf] = *(const v4i*)(xs + ((size_t)phys << 4));
            }
        }
        // MFMAs for k1
#pragma unroll
        for (int mf = 0; mf < 7; ++mf)
#pragma unroll
            for (int of = 0; of < 4; ++of)
                acc[mf][of] = __builtin_amdgcn_mfma_i32_16x16x64_i8(
                    aB[mf], bB[of], acc[mf][of], 0, 0, 0);
    }

    // epilogue: m = mf*16 + q*4 + reg; row = m>=56 (float4-aligned split), no masks
#pragma unroll
    for (int of = 0; of < 4; ++of) {
        int o = (wave * 4 + of) * 16 + lm;
        float s = scaleg[o];
#pragma unroll
        for (int mf = 0; mf < 7; ++mf) {
            int m  = mf * 16 + q * 4;
            int r  = (m >= 56) ? 1 : 0;
            int wb = m - 56 * r;
            float* ob = out + ((size_t)(n * C_ + o) * H_ + h0 + r) * W_ + wb;
            float4 v = {s * (float)acc[mf][of].x, s * (float)acc[mf][of].y,
                        s * (float)acc[mf][of].z, s * (float)acc[mf][of].w};
            *(float4*)ob = v;
        }
    }
}

extern "C" void kernel_launch(void* const* d_in, const int* in_sizes, int n_in,
                              void* d_out, int out_size, void* d_ws, size_t ws_size,
                              hipStream_t stream) {
    const float* x   = (const float*)d_in[0];
    const float* wgt = (const float*)d_in[1];
    float* out = (float*)d_out;
    char* ws = (char*)d_ws;

    char*  sx = ws;
    char*  wb = ws + WB_OFF;
    float* sg = (float*)(ws + SC_OFF);

    zero_halo<<<dim3(58, N_), dim3(256), 0, stream>>>(sx);
    pack_x<<<dim3(49, N_), dim3(256), 0, stream>>>(x, sx);
    pack_w<<<dim3(256), dim3(256), 0, stream>>>(wgt, wb, sg);
    conv_mfma<<<dim3(28, N_), dim3(256), 0, stream>>>(sx, (const v4i*)wb, sg, out);
}